// Round 3
// baseline (153.174 us; speedup 1.0000x reference)
//
#include <hip/hip_runtime.h>
#include <hip/hip_bf16.h>

#define I_DIM 4096
#define J_DIM 4096
#define NPERM0 10
#define NPERM1 10
#define RROWS 4          // output rows per block
#define FUSED_THREADS 512

typedef float  f32x4 __attribute__((ext_vector_type(4)));
typedef int    i32x4 __attribute__((ext_vector_type(4)));

// soft mask: clip((xi-gamma)*sigmoid(x)+gamma, 0, 1) with xi=1.1, gamma=-0.1
__device__ __forceinline__ float soft_mask(float x) {
    float s = 1.0f / (1.0f + __expf(-x));
    return fminf(fmaxf(1.2f * s - 0.1f, 0.0f), 1.0f);
}

// Pass 0: sw = weight * soft_mask(sparse_mask), float4-vectorized.
// weight/mask are single-use -> non-temporal loads (don't pollute L2/L3;
// sw itself is re-read 10x by the fused pass and should stay resident).
__global__ __launch_bounds__(256) void sw_kernel(
    const float* __restrict__ w, const float* __restrict__ m,
    float* __restrict__ sw, int n4) {
    int idx = blockIdx.x * blockDim.x + threadIdx.x;
    if (idx >= n4) return;
    f32x4 wv = __builtin_nontemporal_load(reinterpret_cast<const f32x4*>(w) + idx);
    f32x4 mv = __builtin_nontemporal_load(reinterpret_cast<const f32x4*>(m) + idx);
    f32x4 o;
#pragma unroll
    for (int k = 0; k < 4; ++k) o[k] = wv[k] * soft_mask(mv[k]);
    reinterpret_cast<f32x4*>(sw)[idx] = o;
}

// Fused pass: per block, RROWS output rows. Each thread owns 4 consecutive
// columns (float4 granularity) -> 16B per VMEM instruction.
//   Phase A (row-mix): v[r][c] = sum_p ps0[p,i_r] * sw[perm0[p,i_r], c]
//     stored in LDS as [c][r] so one float4 spans the 4 rows of column c.
//   Phase B (col-mix): out[i_r][c] = sum_q v[r][perm1[q,c]] * ps1[q,c]
//     one ds_read_b128 per (q,c) yields all 4 rows of the gathered column.
__global__ __launch_bounds__(FUSED_THREADS, 4) void fused_kernel(
    const float* __restrict__ sw,
    const float* __restrict__ ps0,   // (NPERM0, I)
    const float* __restrict__ ps1,   // (NPERM1, J)
    const int*   __restrict__ perm0, // (NPERM0, I)
    const int*   __restrict__ perm1, // (NPERM1, J)
    float* __restrict__ out) {
    __shared__ float vlds[J_DIM * RROWS];  // 64 KiB, layout [c][r]

    const int i0 = blockIdx.x * RROWS;

    // Phase A: build v rows into LDS. J/4 = 1024 float4-columns, 2 per thread.
    for (int c4 = threadIdx.x; c4 < J_DIM / 4; c4 += FUSED_THREADS) {
        f32x4 acc[RROWS];
#pragma unroll
        for (int r = 0; r < RROWS; ++r) acc[r] = (f32x4)(0.f);

#pragma unroll
        for (int p = 0; p < NPERM0; ++p) {
#pragma unroll
            for (int r = 0; r < RROWS; ++r) {
                int   row = perm0[p * I_DIM + i0 + r];   // block-uniform -> scalar
                float s   = ps0 [p * I_DIM + i0 + r];    // block-uniform -> scalar
                f32x4 v   = reinterpret_cast<const f32x4*>(
                                sw + (size_t)row * J_DIM)[c4];
                acc[r] += s * v;
            }
        }
        // Transpose 4x4 in registers: column k gets {acc[0].k,..,acc[3].k}.
        f32x4* dst = reinterpret_cast<f32x4*>(&vlds[(size_t)(c4 * 4) * RROWS]);
#pragma unroll
        for (int k = 0; k < 4; ++k) {
            f32x4 t;
            t[0] = acc[0][k]; t[1] = acc[1][k]; t[2] = acc[2][k]; t[3] = acc[3][k];
            dst[k] = t;
        }
    }
    __syncthreads();

    // Phase B: column gather + combine, write out (4 cols per thread).
    const f32x4* L = reinterpret_cast<const f32x4*>(vlds);
    for (int c4 = threadIdx.x; c4 < J_DIM / 4; c4 += FUSED_THREADS) {
        f32x4 o[RROWS];
#pragma unroll
        for (int r = 0; r < RROWS; ++r) o[r] = (f32x4)(0.f);

#pragma unroll
        for (int q = 0; q < NPERM1; ++q) {
            i32x4 pc = reinterpret_cast<const i32x4*>(perm1 + (size_t)q * J_DIM)[c4];
            f32x4 s  = reinterpret_cast<const f32x4*>(ps1 + (size_t)q * J_DIM)[c4];
            f32x4 v0 = L[pc[0]];   // (r0,r1,r2,r3) of gathered column k=0
            f32x4 v1 = L[pc[1]];
            f32x4 v2 = L[pc[2]];
            f32x4 v3 = L[pc[3]];
#pragma unroll
            for (int r = 0; r < RROWS; ++r) {
                o[r][0] += s[0] * v0[r];
                o[r][1] += s[1] * v1[r];
                o[r][2] += s[2] * v2[r];
                o[r][3] += s[3] * v3[r];
            }
        }
#pragma unroll
        for (int r = 0; r < RROWS; ++r) {
            // out is never re-read: non-temporal to avoid evicting sw from L2/L3.
            __builtin_nontemporal_store(
                o[r], reinterpret_cast<f32x4*>(out + (size_t)(i0 + r) * J_DIM) + c4);
        }
    }
}

extern "C" void kernel_launch(void* const* d_in, const int* in_sizes, int n_in,
                              void* d_out, int out_size, void* d_ws, size_t ws_size,
                              hipStream_t stream) {
    const float* weight = (const float*)d_in[0];
    const float* smask  = (const float*)d_in[1];
    const float* ps0    = (const float*)d_in[2];
    const float* ps1    = (const float*)d_in[3];
    const int*   perm0  = (const int*)d_in[4];
    const int*   perm1  = (const int*)d_in[5];
    float* out = (float*)d_out;
    float* sw  = (float*)d_ws;   // needs I*J*4 = 64 MiB scratch

    const int n4 = I_DIM * J_DIM / 4;
    sw_kernel<<<n4 / 256, 256, 0, stream>>>(weight, smask, sw, n4);
    fused_kernel<<<I_DIM / RROWS, FUSED_THREADS, 0, stream>>>(
        sw, ps0, ps1, perm0, perm1, out);
}